// Round 2
// baseline (392.856 us; speedup 1.0000x reference)
//
#include <hip/hip_runtime.h>
#include <hip/hip_cooperative_groups.h>
namespace cg = cooperative_groups;

#define HW 409600
#define NCH 12

// workspace layout (bytes)
#define OFF_TACC   0                     // 16*3 floats
#define OFF_KACC   256                   // 80*3 floats
#define OFF_TFAST  1280                  // 16*3 floats
#define OFF_TFB    1536                  // 16*3 floats
#define OFF_POSF   1792                  // 16 f32
#define OFF_NEGF   1856                  // 16 f32
#define OFF_DONE   1920                  // 16 u32
#define OFF_NEGNUM 1984
#define OFF_SEL1   2048
#define OFF_KREM1  2112
#define OFF_SEL2   2176
#define OFF_KREM2  2240
#define OFF_THR    2304                  // 16 f32
#define OFF_ANYG   2368                  // 1 u32
#define OFF_HA     4096                  // 16*2048 u32
#define OFF_HB     (OFF_HA + 16*2048*4)
#define OFF_HC     (OFF_HB + 16*2048*4)  // 16*1024 u32

__device__ __forceinline__ unsigned flipkey(float x){
  unsigned b = __float_as_uint(x);
  return (b & 0x80000000u) ? ~b : (b | 0x80000000u);   // monotone float->uint
}
__device__ __forceinline__ float unflip(unsigned u){
  unsigned b = (u & 0x80000000u) ? (u ^ 0x80000000u) : ~u;
  return __uint_as_float(b);
}
__device__ __forceinline__ float sigm(float x){
  return __fdividef(1.0f, 1.0f + __expf(-x));
}

// K1 (fused single pass, 6400 blocks x 256, 4 px/thread):
//  - pos/neg counts
//  - kernel-dice sums j=0..4 (mask = selk = sigmoid(text)>0.5 & tm>0.5, OHEM-free)
//  - text-dice sums for BOTH candidate masks:
//      fast:     m = (tm>0.5)   [negnum==negtotal => thr = min neg => sel == tm>0.5]
//      fallback: m = tm (continuous)
//  NO maskb write — generic radix path recomputes predicates from labels/tmask.
__global__ __launch_bounds__(256) void k_main(
    const float* __restrict__ outputs, const float* __restrict__ labels,
    const float* __restrict__ tmask,
    float* __restrict__ posF, float* __restrict__ negF,
    float* __restrict__ tfastA, float* __restrict__ tfbA,
    float* __restrict__ kaccA)
{
  int img = blockIdx.x / 400;        // img = ci*8 + bi
  int blk = blockIdx.x % 400;
  int ci = img >> 3, bi = img & 7;
  const float* ob = outputs + (size_t)(bi*NCH + ci*6)*HW;
  const float* lb = labels  + (size_t)(bi*NCH + ci*6)*HW;
  const float* mp = tmask   + (size_t)bi*HW;
  int px = blk*1024 + (int)threadIdx.x*4;

  float4 ov0 = *(const float4*)(ob + 0*HW + px);
  float4 ov1 = *(const float4*)(ob + 1*HW + px);
  float4 ov2 = *(const float4*)(ob + 2*HW + px);
  float4 ov3 = *(const float4*)(ob + 3*HW + px);
  float4 ov4 = *(const float4*)(ob + 4*HW + px);
  float4 ov5 = *(const float4*)(ob + 5*HW + px);
  float4 lv0 = *(const float4*)(lb + 0*HW + px);
  float4 lv1 = *(const float4*)(lb + 1*HW + px);
  float4 lv2 = *(const float4*)(lb + 2*HW + px);
  float4 lv3 = *(const float4*)(lb + 3*HW + px);
  float4 lv4 = *(const float4*)(lb + 4*HW + px);
  float4 lv5 = *(const float4*)(lb + 5*HW + px);
  float4 mv  = *(const float4*)(mp + px);

  float oo[6][4] = {{ov0.x,ov0.y,ov0.z,ov0.w},{ov1.x,ov1.y,ov1.z,ov1.w},
                    {ov2.x,ov2.y,ov2.z,ov2.w},{ov3.x,ov3.y,ov3.z,ov3.w},
                    {ov4.x,ov4.y,ov4.z,ov4.w},{ov5.x,ov5.y,ov5.z,ov5.w}};
  float ll[6][4] = {{lv0.x,lv0.y,lv0.z,lv0.w},{lv1.x,lv1.y,lv1.z,lv1.w},
                    {lv2.x,lv2.y,lv2.z,lv2.w},{lv3.x,lv3.y,lv3.z,lv3.w},
                    {lv4.x,lv4.y,lv4.z,lv4.w},{lv5.x,lv5.y,lv5.z,lv5.w}};
  float tmv[4] = {mv.x,mv.y,mv.z,mv.w};

  float ka0=0,ka1=0,ka2=0,ka3=0,ka4=0;
  float kb0=0,kb1=0,kb2=0,kb3=0,kb4=0;
  float kc0=0,kc1=0,kc2=0,kc3=0,kc4=0;
  float af=0,bf=0,cf=0;          // text fast
  float ab_=0,bb_=0,cb_=0;       // text fallback
  unsigned pos=0, neg=0;

  #pragma unroll
  for (int c=0;c<4;c++){
    float t  = oo[5][c];
    float g  = ll[5][c];
    float tm = tmv[c];
    bool tpos  = (tm > 0.5f);
    bool isneg = (g <= 0.5f);
    bool selk  = (t > 0.0f) && tpos;
    pos += (unsigned)((!isneg) && tpos);
    neg += (unsigned)isneg;

    float s5 = sigm(t);
    float mf = tpos ? 1.0f : 0.0f;
    af += mf * (s5*g);
    bf += mf * (s5*s5);
    cf += mf * (g*g);
    float pfb = s5*tm, tfb = g*tm;
    ab_ += pfb*tfb; bb_ += pfb*pfb; cb_ += tfb*tfb;
    float mk = selk ? 1.0f : 0.0f;
    {
      float s, l;
      s = sigm(oo[0][c]); l = ll[0][c];
      ka0 += mk*(s*l); kb0 += mk*(s*s); kc0 += mk*(l*l);
      s = sigm(oo[1][c]); l = ll[1][c];
      ka1 += mk*(s*l); kb1 += mk*(s*s); kc1 += mk*(l*l);
      s = sigm(oo[2][c]); l = ll[2][c];
      ka2 += mk*(s*l); kb2 += mk*(s*s); kc2 += mk*(l*l);
      s = sigm(oo[3][c]); l = ll[3][c];
      ka3 += mk*(s*l); kb3 += mk*(s*s); kc3 += mk*(l*l);
      s = sigm(oo[4][c]); l = ll[4][c];
      ka4 += mk*(s*l); kb4 += mk*(s*s); kc4 += mk*(l*l);
    }
  }

  float red[23] = {af,bf,cf, ab_,bb_,cb_,
                   ka0,kb0,kc0, ka1,kb1,kc1, ka2,kb2,kc2,
                   ka3,kb3,kc3, ka4,kb4,kc4,
                   (float)pos, (float)neg};
  #pragma unroll
  for (int k=0;k<23;k++){
    #pragma unroll
    for (int o=32;o;o>>=1) red[k] += __shfl_down(red[k],o,64);
  }
  __shared__ float sred[4][23];
  int wv = threadIdx.x >> 6, ln = threadIdx.x & 63;
  if (ln==0){
    #pragma unroll
    for (int k=0;k<23;k++) sred[wv][k] = red[k];
  }
  __syncthreads();
  int t = threadIdx.x;
  if (t < 23){
    float v = sred[0][t]+sred[1][t]+sred[2][t]+sred[3][t];
    float* dst;
    if      (t < 3)  dst = tfastA + img*3 + t;
    else if (t < 6)  dst = tfbA   + img*3 + (t-3);
    else if (t < 21) dst = kaccA  + img*15 + (t-6);
    else if (t ==21) dst = posF + img;
    else             dst = negF + img;
    atomicAdd(dst, v);
  }
}

template<int NB>
__device__ void scan_desc(const unsigned* h, unsigned k, unsigned* selOut, unsigned* kremOut)
{
  const int PER = NB/256;
  int t = threadIdx.x;
  unsigned s=0;
  #pragma unroll
  for (int j=0;j<PER;j++) s += h[t*PER+j];
  __shared__ unsigned cs[256];
  cs[t]=s; __syncthreads();
  if (t==0){
    unsigned cum=0, ch=0, kin=k;
    for (int c=255;c>=0;c--){
      if (cum + cs[c] >= k){ ch=(unsigned)c; kin=k-cum; break; }
      cum += cs[c];
    }
    unsigned cum2=0, sel=ch*PER, kr=1;
    for (int x=PER-1;x>=0;x--){
      unsigned v = h[ch*PER+x];
      cum2 += v;
      if (cum2 >= kin){ sel=ch*PER+(unsigned)x; kr = kin - (cum2 - v); break; }
    }
    *selOut = sel; *kremOut = kr;
  }
  __syncthreads();
}

__device__ void do_final(const float* tacc, const float* kacc, float* out)
{
  const float EPSF = 1e-4f;
  float ltA[2], lkA[2];
  for (int i=0;i<2;i++){
    float lt=0.f;
    for (int b=0;b<8;b++){
      int img=i*8+b;
      float a=tacc[img*3], p2=tacc[img*3+1]+EPSF, t2=tacc[img*3+2]+EPSF;
      lt += 1.f - 2.f*a/(p2+t2);
    }
    lt *= 0.125f;
    float lk=0.f;
    for (int b=0;b<8;b++) for (int k=0;k<5;k++){
      int idx=((i*8+b)*5+k)*3;
      float a=kacc[idx], p2=kacc[idx+1]+EPSF, t2=kacc[idx+2]+EPSF;
      lk += 1.f - 2.f*a/(p2+t2);
    }
    lk /= 40.f;
    ltA[i]=lt; lkA[i]=lk;
  }
  float l0 = 0.7f*ltA[0] + 0.3f*lkA[0];
  float l1 = 0.7f*ltA[1] + 0.3f*lkA[1];
  out[0]=0.5f*(l0+l1);
  out[1]=0.5f*(ltA[0]+ltA[1]);
  out[2]=0.5f*(lkA[0]+lkA[1]);
}

// K2 (cooperative): decide + (dormant) 3-pass radix OHEM + text dice + finalize.
// Fast path (this data): decide -> grid.sync -> flag read -> finalize. Few us.
// Generic path recomputes neg/tm predicates from labels/tmask (no maskb needed).
__global__ __launch_bounds__(256) void k_tail(
    const float* __restrict__ outputs, const float* __restrict__ labels,
    const float* __restrict__ tmask, char* __restrict__ ws, float* __restrict__ out)
{
  cg::grid_group grid = cg::this_grid();
  float* tacc      = (float*)(ws + OFF_TACC);
  float* kacc      = (float*)(ws + OFF_KACC);
  float* tfastA    = (float*)(ws + OFF_TFAST);
  float* tfbA      = (float*)(ws + OFF_TFB);
  float* posF      = (float*)(ws + OFF_POSF);
  float* negF      = (float*)(ws + OFF_NEGF);
  unsigned* doneA  = (unsigned*)(ws + OFF_DONE);
  unsigned* negnumA= (unsigned*)(ws + OFF_NEGNUM);
  unsigned* sel1A  = (unsigned*)(ws + OFF_SEL1);
  unsigned* krem1A = (unsigned*)(ws + OFF_KREM1);
  unsigned* sel2A  = (unsigned*)(ws + OFF_SEL2);
  unsigned* krem2A = (unsigned*)(ws + OFF_KREM2);
  float* thrA      = (float*)(ws + OFF_THR);
  unsigned* anyG   = (unsigned*)(ws + OFF_ANYG);
  unsigned* histA  = (unsigned*)(ws + OFF_HA);
  unsigned* histB  = (unsigned*)(ws + OFF_HB);
  unsigned* histC  = (unsigned*)(ws + OFF_HC);

  // ---- phase 0: per-image decision (block 0) ----
  if (blockIdx.x == 0){
    int t = threadIdx.x;
    unsigned d = 1u;
    if (t < 16){
      float pos = posF[t], negt = negF[t];      // exact ints in f32
      float nn = fminf(pos*3.0f, negt);
      bool fb   = (pos == 0.0f) || (nn == 0.0f);
      bool fast = (!fb) && (nn == negt);
      d = (fb || fast) ? 1u : 0u;
      doneA[t] = d;
      negnumA[t] = d ? 1u : (unsigned)(nn + 0.5f);
      thrA[t] = 0.0f;
      if (d){
        const float* src = fb ? (tfbA + t*3) : (tfastA + t*3);
        tacc[t*3+0] = src[0];
        tacc[t*3+1] = src[1];
        tacc[t*3+2] = src[2];
      }
    }
    unsigned long long nd = __ballot((t < 16) && (d == 0u));
    if (t == 0) anyG[0] = (nd != 0ull) ? 1u : 0u;
    __threadfence();
  }
  grid.sync();

  if (anyG[0] == 0u){
    if (blockIdx.x == 0 && threadIdx.x == 0) do_final(tacc, kacc, out);
    return;
  }

  // ================= generic radix path (dormant for this data) =================
  // zero hists (HA+HB+HC contiguous: 81920 words)
  for (int i = blockIdx.x*256 + threadIdx.x; i < 81920; i += gridDim.x*256)
    histA[i] = 0u;
  grid.sync();

  __shared__ unsigned lh[2048];

  // pass A hist: key[31:21] of negatives
  for (int tile = blockIdx.x; tile < 800; tile += gridDim.x){
    int img = tile/50;
    if (doneA[img]) continue;
    int blk = tile%50;
    int ci = img>>3, bi = img&7;
    const float* tp = outputs + (size_t)(bi*NCH + ci*6 + 5)*HW;
    const float* gp = labels  + (size_t)(bi*NCH + ci*6 + 5)*HW;
    for (int j=threadIdx.x; j<2048; j+=256) lh[j]=0u;
    __syncthreads();
    for (int it=0; it<8; it++){
      int px = blk*8192 + it*1024 + (int)threadIdx.x*4;
      float4 tv = *(const float4*)(tp+px);
      float4 gv = *(const float4*)(gp+px);
      float tt[4]={tv.x,tv.y,tv.z,tv.w};
      float gg[4]={gv.x,gv.y,gv.z,gv.w};
      #pragma unroll
      for (int c=0;c<4;c++)
        if (gg[c] <= 0.5f) atomicAdd(&lh[flipkey(tt[c]) >> 21], 1u);
    }
    __syncthreads();
    unsigned* gh = histA + (size_t)img*2048u;
    for (int j=threadIdx.x; j<2048; j+=256){
      unsigned v = lh[j];
      if (v) atomicAdd(&gh[j], v);
    }
    __syncthreads();
  }
  grid.sync();

  if (blockIdx.x < 16 && !doneA[blockIdx.x])
    scan_desc<2048>(histA + (size_t)blockIdx.x*2048u, negnumA[blockIdx.x],
                    &sel1A[blockIdx.x], &krem1A[blockIdx.x]);
  grid.sync();

  // pass B hist: key[20:10] where key[31:21]==sel1
  for (int tile = blockIdx.x; tile < 800; tile += gridDim.x){
    int img = tile/50;
    if (doneA[img]) continue;
    int blk = tile%50;
    int ci = img>>3, bi = img&7;
    unsigned sel1 = sel1A[img];
    const float* tp = outputs + (size_t)(bi*NCH + ci*6 + 5)*HW;
    const float* gp = labels  + (size_t)(bi*NCH + ci*6 + 5)*HW;
    for (int j=threadIdx.x; j<2048; j+=256) lh[j]=0u;
    __syncthreads();
    for (int it=0; it<8; it++){
      int px = blk*8192 + it*1024 + (int)threadIdx.x*4;
      float4 tv = *(const float4*)(tp+px);
      float4 gv = *(const float4*)(gp+px);
      float tt[4]={tv.x,tv.y,tv.z,tv.w};
      float gg[4]={gv.x,gv.y,gv.z,gv.w};
      #pragma unroll
      for (int c=0;c<4;c++){
        if (gg[c] <= 0.5f){
          unsigned key = flipkey(tt[c]);
          if ((key>>21) == sel1) atomicAdd(&lh[(key>>10) & 0x7FFu], 1u);
        }
      }
    }
    __syncthreads();
    unsigned* gh = histB + (size_t)img*2048u;
    for (int j=threadIdx.x; j<2048; j+=256){
      unsigned v = lh[j];
      if (v) atomicAdd(&gh[j], v);
    }
    __syncthreads();
  }
  grid.sync();

  if (blockIdx.x < 16 && !doneA[blockIdx.x])
    scan_desc<2048>(histB + (size_t)blockIdx.x*2048u, krem1A[blockIdx.x],
                    &sel2A[blockIdx.x], &krem2A[blockIdx.x]);
  grid.sync();

  // pass C hist: key[9:0] where key[31:10]==(sel1<<11)|sel2
  for (int tile = blockIdx.x; tile < 800; tile += gridDim.x){
    int img = tile/50;
    if (doneA[img]) continue;
    int blk = tile%50;
    int ci = img>>3, bi = img&7;
    unsigned p22 = (sel1A[img]<<11) | sel2A[img];
    const float* tp = outputs + (size_t)(bi*NCH + ci*6 + 5)*HW;
    const float* gp = labels  + (size_t)(bi*NCH + ci*6 + 5)*HW;
    for (int j=threadIdx.x; j<1024; j+=256) lh[j]=0u;
    __syncthreads();
    for (int it=0; it<8; it++){
      int px = blk*8192 + it*1024 + (int)threadIdx.x*4;
      float4 tv = *(const float4*)(tp+px);
      float4 gv = *(const float4*)(gp+px);
      float tt[4]={tv.x,tv.y,tv.z,tv.w};
      float gg[4]={gv.x,gv.y,gv.z,gv.w};
      #pragma unroll
      for (int c=0;c<4;c++){
        if (gg[c] <= 0.5f){
          unsigned key = flipkey(tt[c]);
          if ((key>>10) == p22) atomicAdd(&lh[key & 0x3FFu], 1u);
        }
      }
    }
    __syncthreads();
    unsigned* gh = histC + (size_t)img*1024u;
    for (int j=threadIdx.x; j<1024; j+=256){
      unsigned v = lh[j];
      if (v) atomicAdd(&gh[j], v);
    }
    __syncthreads();
  }
  grid.sync();

  if (blockIdx.x < 16 && !doneA[blockIdx.x]){
    __shared__ unsigned sel3, kr;
    scan_desc<1024>(histC + (size_t)blockIdx.x*1024u, krem2A[blockIdx.x], &sel3, &kr);
    if (threadIdx.x==0){
      unsigned key = (sel1A[blockIdx.x]<<21) | (sel2A[blockIdx.x]<<10) | sel3;
      thrA[blockIdx.x] = unflip(key);
    }
  }
  grid.sync();

  // generic text dice
  for (int tile = blockIdx.x; tile < 800; tile += gridDim.x){
    int img = tile/50;
    if (doneA[img]) continue;
    int blk = tile%50;
    int ci = img>>3, bi = img&7;
    const float* tp = outputs + (size_t)(bi*NCH + ci*6 + 5)*HW;
    const float* gp = labels  + (size_t)(bi*NCH + ci*6 + 5)*HW;
    const float* mp = tmask   + (size_t)bi*HW;
    float thr = thrA[img];
    float sa=0.f, sb=0.f, sc=0.f;
    for (int it=0; it<8; it++){
      int px = blk*8192 + it*1024 + (int)threadIdx.x*4;
      float4 pv = *(const float4*)(tp+px);
      float4 gv = *(const float4*)(gp+px);
      float4 mv = *(const float4*)(mp+px);
      float pa[4]={pv.x,pv.y,pv.z,pv.w};
      float ga[4]={gv.x,gv.y,gv.z,gv.w};
      float ma[4]={mv.x,mv.y,mv.z,mv.w};
      #pragma unroll
      for (int c=0;c<4;c++){
        float m = (((pa[c] >= thr) || (ga[c] > 0.5f)) && (ma[c] > 0.5f)) ? 1.0f : 0.0f;
        float p = sigm(pa[c]) * m;
        float tt = ga[c]*m;
        sa += p*tt; sb += p*p; sc += tt*tt;
      }
    }
    #pragma unroll
    for (int o=32;o;o>>=1){
      sa += __shfl_down(sa,o,64); sb += __shfl_down(sb,o,64); sc += __shfl_down(sc,o,64);
    }
    __shared__ float ra[4], rb[4], rc[4];
    int wv = threadIdx.x>>6, ln = threadIdx.x&63;
    if (ln==0){ ra[wv]=sa; rb[wv]=sb; rc[wv]=sc; }
    __syncthreads();
    if (threadIdx.x==0){
      float* acc = tacc + img*3;
      atomicAdd(acc+0, ra[0]+ra[1]+ra[2]+ra[3]);
      atomicAdd(acc+1, rb[0]+rb[1]+rb[2]+rb[3]);
      atomicAdd(acc+2, rc[0]+rc[1]+rc[2]+rc[3]);
    }
    __syncthreads();
  }
  grid.sync();

  if (blockIdx.x == 0 && threadIdx.x == 0) do_final(tacc, kacc, out);
}

extern "C" void kernel_launch(void* const* d_in, const int* in_sizes, int n_in,
                              void* d_out, int out_size, void* d_ws, size_t ws_size,
                              hipStream_t stream)
{
  const float* outputs = (const float*)d_in[0];
  const float* labels  = (const float*)d_in[1];
  const float* tmask   = (const float*)d_in[2];
  float* out = (float*)d_out;
  char* ws = (char*)d_ws;
  float* posF      = (float*)(ws + OFF_POSF);
  float* negF      = (float*)(ws + OFF_NEGF);
  float* tfastA    = (float*)(ws + OFF_TFAST);
  float* tfbA      = (float*)(ws + OFF_TFB);
  float* kacc      = (float*)(ws + OFF_KACC);

  // zero only the atomically-accumulated meta region (2 KiB); hists are zeroed
  // lazily inside k_tail's generic path.
  hipMemsetAsync(ws, 0, 2048, stream);
  k_main<<<6400,256,0,stream>>>(outputs, labels, tmask, posF, negF,
                                tfastA, tfbA, kacc);
  void* args[] = { (void*)&outputs, (void*)&labels, (void*)&tmask,
                   (void*)&ws, (void*)&out };
  hipLaunchCooperativeKernel((const void*)k_tail, dim3(256), dim3(256),
                             args, 0, stream);
}

// Round 3
// 346.481 us; speedup vs baseline: 1.1338x; 1.1338x over previous
//
#include <hip/hip_runtime.h>

#define HW 409600
#define NCH 12

// workspace layout (bytes)
#define OFF_PSLOT  0                       // 3200 blocks * 23 f32 = 294400 B
#define OFF_TACC   294912                  // 16*3 f32
#define OFF_KACC   295168                  // 16*15 f32
#define OFF_CNT    296192                  // 1 u32

__device__ __forceinline__ unsigned flipkey(float x){
  unsigned b = __float_as_uint(x);
  return (b & 0x80000000u) ? ~b : (b | 0x80000000u);   // monotone float->uint
}
__device__ __forceinline__ float unflip(unsigned u){
  unsigned b = (u & 0x80000000u) ? (u ^ 0x80000000u) : ~u;
  return __uint_as_float(b);
}
__device__ __forceinline__ float sigm(float x){
  return __fdividef(1.0f, 1.0f + __expf(-x));
}

// K1 (fused single pass, 3200 blocks x 256, 8 px/thread in 2 batches):
// per image: pos/neg counts, kernel-dice sums j=0..4 (mask=selk, OHEM-free),
// text-dice sums for BOTH candidate masks (fast: tm>0.5, fallback: tm).
// Partials go to per-block slots (no atomics, no memset needed).
__global__ __launch_bounds__(256) void k_main(
    const float* __restrict__ outputs, const float* __restrict__ labels,
    const float* __restrict__ tmask, float* __restrict__ pslot,
    unsigned* __restrict__ cnt)
{
  if (blockIdx.x == 0 && threadIdx.x == 0) *cnt = 0u;   // reset tail counter
  int img = blockIdx.x / 200;        // img = ci*8 + bi
  int blk = blockIdx.x % 200;
  int ci = img >> 3, bi = img & 7;
  const float* ob = outputs + (size_t)(bi*NCH + ci*6)*HW;
  const float* lb = labels  + (size_t)(bi*NCH + ci*6)*HW;
  const float* mp = tmask   + (size_t)bi*HW;

  float ka0=0,ka1=0,ka2=0,ka3=0,ka4=0;
  float kb0=0,kb1=0,kb2=0,kb3=0,kb4=0;
  float kc0=0,kc1=0,kc2=0,kc3=0,kc4=0;
  float af=0,bf=0,cf=0;          // text fast
  float ab_=0,bb_=0,cb_=0;       // text fallback
  unsigned pos=0, neg=0;

  #pragma unroll
  for (int it=0; it<2; it++){
    int px = blk*2048 + it*1024 + (int)threadIdx.x*4;
    float4 ov0 = *(const float4*)(ob + 0*HW + px);
    float4 ov1 = *(const float4*)(ob + 1*HW + px);
    float4 ov2 = *(const float4*)(ob + 2*HW + px);
    float4 ov3 = *(const float4*)(ob + 3*HW + px);
    float4 ov4 = *(const float4*)(ob + 4*HW + px);
    float4 ov5 = *(const float4*)(ob + 5*HW + px);
    float4 lv0 = *(const float4*)(lb + 0*HW + px);
    float4 lv1 = *(const float4*)(lb + 1*HW + px);
    float4 lv2 = *(const float4*)(lb + 2*HW + px);
    float4 lv3 = *(const float4*)(lb + 3*HW + px);
    float4 lv4 = *(const float4*)(lb + 4*HW + px);
    float4 lv5 = *(const float4*)(lb + 5*HW + px);
    float4 mv  = *(const float4*)(mp + px);

    float oo[6][4] = {{ov0.x,ov0.y,ov0.z,ov0.w},{ov1.x,ov1.y,ov1.z,ov1.w},
                      {ov2.x,ov2.y,ov2.z,ov2.w},{ov3.x,ov3.y,ov3.z,ov3.w},
                      {ov4.x,ov4.y,ov4.z,ov4.w},{ov5.x,ov5.y,ov5.z,ov5.w}};
    float ll[6][4] = {{lv0.x,lv0.y,lv0.z,lv0.w},{lv1.x,lv1.y,lv1.z,lv1.w},
                      {lv2.x,lv2.y,lv2.z,lv2.w},{lv3.x,lv3.y,lv3.z,lv3.w},
                      {lv4.x,lv4.y,lv4.z,lv4.w},{lv5.x,lv5.y,lv5.z,lv5.w}};
    float tmv[4] = {mv.x,mv.y,mv.z,mv.w};

    #pragma unroll
    for (int c=0;c<4;c++){
      float t  = oo[5][c];
      float g  = ll[5][c];
      float tm = tmv[c];
      bool tpos  = (tm > 0.5f);
      bool isneg = (g <= 0.5f);
      bool selk  = (t > 0.0f) && tpos;
      pos += (unsigned)((!isneg) && tpos);
      neg += (unsigned)isneg;

      float s5 = sigm(t);
      float mf = tpos ? 1.0f : 0.0f;
      af += mf * (s5*g);
      bf += mf * (s5*s5);
      cf += mf * (g*g);
      float pfb = s5*tm, tfb = g*tm;
      ab_ += pfb*tfb; bb_ += pfb*pfb; cb_ += tfb*tfb;
      float mk = selk ? 1.0f : 0.0f;
      {
        float s, l;
        s = sigm(oo[0][c]); l = ll[0][c];
        ka0 += mk*(s*l); kb0 += mk*(s*s); kc0 += mk*(l*l);
        s = sigm(oo[1][c]); l = ll[1][c];
        ka1 += mk*(s*l); kb1 += mk*(s*s); kc1 += mk*(l*l);
        s = sigm(oo[2][c]); l = ll[2][c];
        ka2 += mk*(s*l); kb2 += mk*(s*s); kc2 += mk*(l*l);
        s = sigm(oo[3][c]); l = ll[3][c];
        ka3 += mk*(s*l); kb3 += mk*(s*s); kc3 += mk*(l*l);
        s = sigm(oo[4][c]); l = ll[4][c];
        ka4 += mk*(s*l); kb4 += mk*(s*s); kc4 += mk*(l*l);
      }
    }
  }

  float red[23] = {af,bf,cf, ab_,bb_,cb_,
                   ka0,kb0,kc0, ka1,kb1,kc1, ka2,kb2,kc2,
                   ka3,kb3,kc3, ka4,kb4,kc4,
                   (float)pos, (float)neg};
  #pragma unroll
  for (int k=0;k<23;k++){
    #pragma unroll
    for (int o=32;o;o>>=1) red[k] += __shfl_down(red[k],o,64);
  }
  __shared__ float sred[4][23];
  int wv = threadIdx.x >> 6, ln = threadIdx.x & 63;
  if (ln==0){
    #pragma unroll
    for (int k=0;k<23;k++) sred[wv][k] = red[k];
  }
  __syncthreads();
  int t = threadIdx.x;
  if (t < 23)
    pslot[(size_t)blockIdx.x*23 + t] = sred[0][t]+sred[1][t]+sred[2][t]+sred[3][t];
}

template<int NB>
__device__ void scan_desc(const unsigned* h, unsigned k, unsigned* selOut, unsigned* kremOut)
{
  const int PER = NB/256;
  int t = threadIdx.x;
  unsigned s=0;
  #pragma unroll
  for (int j=0;j<PER;j++) s += h[t*PER+j];
  __shared__ unsigned cs[256];
  cs[t]=s; __syncthreads();
  if (t==0){
    unsigned cum=0, ch=0, kin=k;
    for (int c=255;c>=0;c--){
      if (cum + cs[c] >= k){ ch=(unsigned)c; kin=k-cum; break; }
      cum += cs[c];
    }
    unsigned cum2=0, sel=ch*PER, kr=1;
    for (int x=PER-1;x>=0;x--){
      unsigned v = h[ch*PER+x];
      cum2 += v;
      if (cum2 >= kin){ sel=ch*PER+(unsigned)x; kr = kin - (cum2 - v); break; }
    }
    *selOut = sel; *kremOut = kr;
  }
  __syncthreads();
}

__device__ void do_final(const float* tacc, const float* kacc, float* out)
{
  const float EPSF = 1e-4f;
  float ltA[2], lkA[2];
  for (int i=0;i<2;i++){
    float lt=0.f;
    for (int b=0;b<8;b++){
      int img=i*8+b;
      float a=tacc[img*3], p2=tacc[img*3+1]+EPSF, t2=tacc[img*3+2]+EPSF;
      lt += 1.f - 2.f*a/(p2+t2);
    }
    lt *= 0.125f;
    float lk=0.f;
    for (int b=0;b<8;b++) for (int k=0;k<5;k++){
      int idx=((i*8+b)*5+k)*3;
      float a=kacc[idx], p2=kacc[idx+1]+EPSF, t2=kacc[idx+2]+EPSF;
      lk += 1.f - 2.f*a/(p2+t2);
    }
    lk /= 40.f;
    ltA[i]=lt; lkA[i]=lk;
  }
  float l0 = 0.7f*ltA[0] + 0.3f*lkA[0];
  float l1 = 0.7f*ltA[1] + 0.3f*lkA[1];
  out[0]=0.5f*(l0+l1);
  out[1]=0.5f*(ltA[0]+ltA[1]);
  out[2]=0.5f*(lkA[0]+lkA[1]);
}

// K2 (normal launch, 16 blocks, one per image — all trivially co-resident on
// 256 CUs). Each block: reduce its 200 partial slots, decide OHEM mode, write
// kacc + tacc. Generic mode (dormant on this data): full 3-pass radix with LDS
// histograms inside the block, then text dice. Block 0 waits on a device-scope
// counter, then finalizes.
__global__ __launch_bounds__(256) void k_tail(
    const float* __restrict__ outputs, const float* __restrict__ labels,
    const float* __restrict__ tmask, char* __restrict__ ws, float* __restrict__ out)
{
  float* pslot = (float*)(ws + OFF_PSLOT);
  float* tacc  = (float*)(ws + OFF_TACC);
  float* kacc  = (float*)(ws + OFF_KACC);
  unsigned* cnt= (unsigned*)(ws + OFF_CNT);
  int img = blockIdx.x;
  int t = threadIdx.x;
  int ci = img>>3, bi = img&7;

  // --- deterministic reduce of this image's 200 slots (23 columns) ---
  const float* ps = pslot + (size_t)img*200*23;
  __shared__ float part[8][23];
  __shared__ float rsum[23];
  int g = t/23, c = t - g*23;
  if (g < 8){
    float s = 0.f;
    for (int r=g; r<200; r+=8) s += ps[r*23 + c];
    part[g][c] = s;
  }
  __syncthreads();
  if (t < 23){
    float s = 0.f;
    #pragma unroll
    for (int q=0;q<8;q++) s += part[q][t];
    rsum[t] = s;
  }
  __syncthreads();

  if (t >= 6 && t < 21) kacc[img*15 + (t-6)] = rsum[t];

  __shared__ unsigned smode;    // 0=generic, 1=fast, 2=fallback
  __shared__ unsigned snegnum;
  if (t==0){
    float pos = rsum[21], negt = rsum[22];   // exact ints in f32
    float nn = fminf(pos*3.0f, negt);
    bool fb   = (pos == 0.0f) || (nn == 0.0f);
    bool fast = (!fb) && (nn == negt);
    smode = fb ? 2u : (fast ? 1u : 0u);
    snegnum = (unsigned)(nn + 0.5f);
  }
  __syncthreads();
  unsigned mode = smode;

  if (mode){
    // fast (thr = min neg => sel == tm>0.5) or fallback (sel = tm)
    if (t < 3) tacc[img*3 + t] = rsum[(mode==2u ? 3 : 0) + t];
  } else {
    // ================= generic radix path (dormant for this data) ==========
    const float* tp = outputs + (size_t)(bi*NCH + ci*6 + 5)*HW;
    const float* gp = labels  + (size_t)(bi*NCH + ci*6 + 5)*HW;
    const float* mp = tmask   + (size_t)bi*HW;
    __shared__ unsigned lh[2048];
    __shared__ unsigned sel1, krem1, sel2, krem2, sel3, krem3;

    // pass A: key[31:21] of negatives
    for (int j=t; j<2048; j+=256) lh[j]=0u;
    __syncthreads();
    for (int px=t*4; px<HW; px+=1024){
      float4 tv = *(const float4*)(tp+px);
      float4 gv = *(const float4*)(gp+px);
      float tt[4]={tv.x,tv.y,tv.z,tv.w};
      float gg[4]={gv.x,gv.y,gv.z,gv.w};
      #pragma unroll
      for (int k=0;k<4;k++)
        if (gg[k] <= 0.5f) atomicAdd(&lh[flipkey(tt[k]) >> 21], 1u);
    }
    __syncthreads();
    scan_desc<2048>(lh, snegnum, &sel1, &krem1);

    // pass B: key[20:10] where key[31:21]==sel1
    unsigned s1 = sel1;
    unsigned k1 = krem1;
    for (int j=t; j<2048; j+=256) lh[j]=0u;
    __syncthreads();
    for (int px=t*4; px<HW; px+=1024){
      float4 tv = *(const float4*)(tp+px);
      float4 gv = *(const float4*)(gp+px);
      float tt[4]={tv.x,tv.y,tv.z,tv.w};
      float gg[4]={gv.x,gv.y,gv.z,gv.w};
      #pragma unroll
      for (int k=0;k<4;k++){
        if (gg[k] <= 0.5f){
          unsigned key = flipkey(tt[k]);
          if ((key>>21) == s1) atomicAdd(&lh[(key>>10) & 0x7FFu], 1u);
        }
      }
    }
    __syncthreads();
    scan_desc<2048>(lh, k1, &sel2, &krem2);

    // pass C: key[9:0] where key[31:10]==(sel1<<11)|sel2
    unsigned p22 = (s1<<11) | sel2;
    unsigned k2 = krem2;
    for (int j=t; j<1024; j+=256) lh[j]=0u;
    __syncthreads();
    for (int px=t*4; px<HW; px+=1024){
      float4 tv = *(const float4*)(tp+px);
      float4 gv = *(const float4*)(gp+px);
      float tt[4]={tv.x,tv.y,tv.z,tv.w};
      float gg[4]={gv.x,gv.y,gv.z,gv.w};
      #pragma unroll
      for (int k=0;k<4;k++){
        if (gg[k] <= 0.5f){
          unsigned key = flipkey(tt[k]);
          if ((key>>10) == p22) atomicAdd(&lh[key & 0x3FFu], 1u);
        }
      }
    }
    __syncthreads();
    scan_desc<1024>(lh, k2, &sel3, &krem3);

    float thr = unflip((s1<<21) | (sel2<<10) | sel3);

    // text dice with OHEM threshold
    float sa=0.f, sb=0.f, sc=0.f;
    for (int px=t*4; px<HW; px+=1024){
      float4 pv = *(const float4*)(tp+px);
      float4 gv = *(const float4*)(gp+px);
      float4 mv = *(const float4*)(mp+px);
      float pa[4]={pv.x,pv.y,pv.z,pv.w};
      float ga[4]={gv.x,gv.y,gv.z,gv.w};
      float ma[4]={mv.x,mv.y,mv.z,mv.w};
      #pragma unroll
      for (int k=0;k<4;k++){
        float m = (((pa[k] >= thr) || (ga[k] > 0.5f)) && (ma[k] > 0.5f)) ? 1.0f : 0.0f;
        float p = sigm(pa[k]) * m;
        float tt = ga[k]*m;
        sa += p*tt; sb += p*p; sc += tt*tt;
      }
    }
    #pragma unroll
    for (int o=32;o;o>>=1){
      sa += __shfl_down(sa,o,64); sb += __shfl_down(sb,o,64); sc += __shfl_down(sc,o,64);
    }
    __shared__ float ra[4], rb[4], rc[4];
    int wv = t>>6, ln = t&63;
    if (ln==0){ ra[wv]=sa; rb[wv]=sb; rc[wv]=sc; }
    __syncthreads();
    if (t==0){
      tacc[img*3+0] = ra[0]+ra[1]+ra[2]+ra[3];
      tacc[img*3+1] = rb[0]+rb[1]+rb[2]+rb[3];
      tacc[img*3+2] = rc[0]+rc[1]+rc[2]+rc[3];
    }
  }

  // signal completion (device scope), block 0 finalizes
  __threadfence();
  __syncthreads();
  if (t==0) atomicAdd(cnt, 1u);
  if (img==0 && t==0){
    while (atomicAdd(cnt, 0u) < 16u) { __builtin_amdgcn_s_sleep(8); }
    __threadfence();
    do_final(tacc, kacc, out);
  }
}

extern "C" void kernel_launch(void* const* d_in, const int* in_sizes, int n_in,
                              void* d_out, int out_size, void* d_ws, size_t ws_size,
                              hipStream_t stream)
{
  const float* outputs = (const float*)d_in[0];
  const float* labels  = (const float*)d_in[1];
  const float* tmask   = (const float*)d_in[2];
  float* out = (float*)d_out;
  char* ws = (char*)d_ws;
  float* pslot  = (float*)(ws + OFF_PSLOT);
  unsigned* cnt = (unsigned*)(ws + OFF_CNT);

  k_main<<<3200,256,0,stream>>>(outputs, labels, tmask, pslot, cnt);
  k_tail<<<16,256,0,stream>>>(outputs, labels, tmask, ws, out);
}